// Round 9
// baseline (91.838 us; speedup 1.0000x reference)
//
#include <hip/hip_runtime.h>
#include <hip/hip_bf16.h>

// Problem constants (match setup_inputs): N=8192 rows, D=512 dims, C=100 classes.
constexpr int N = 8192;
constexpr int D = 512;
constexpr int C = 100;
constexpr int CAP = 256;             // per-class list capacity (mean 82, ~19 sigma)
constexpr int SLICES = 4;            // dim slices (128 dims each)
constexpr int SLICE_D = D / SLICES;  // 128
constexpr int ROWBLKS = N / 4;       // 2048 row blocks (4 waves, one wave per row)
constexpr int SCANBLKS = C;          // 100 list-builder blocks
constexpr int GBLOCKS = C * SLICES;  // 400 gather blocks

// Workspace layout (bytes) — nothing pre-zeroed by host (no memset node):
//   [0, 400)       counts[C]   (int)   — plain-stored by K1 scan blocks
//   [400, 404)     done        (int)   — zeroed by K1 block 0
//   [404, 408)     Bsum        (float) — zeroed by K1 block 0
//   [512, 2560)    Tsum[D]     (float) — zeroed by K1 block 0
//   [2560, 35328)  invn[N]     (float)
//   [35328,137728) list[C][CAP](int)
constexpr size_t OFF_DONE = 400;
constexpr size_t OFF_BSUM = 404;
constexpr size_t OFF_TSUM = 512;
constexpr size_t OFF_INVN = 2560;
constexpr size_t OFF_LIST = 35328;

// K1 (2148 blocks):
//  - block 0 additionally zeroes [done|Bsum|Tsum] (540 words at int-offset 100).
//  - blocks [0, ROWBLKS): one 64-lane wave per row computes inv norm.
//  - blocks [ROWBLKS, ROWBLKS+C): block per class scans labels, builds
//    list[c] + counts[c] via an LDS-local counter (no global atomics).
__global__ __launch_bounds__(256) void norm_list_kernel(
    const float* __restrict__ e,
    const int* __restrict__ y,
    float* __restrict__ invn,
    int* __restrict__ counts,
    int* __restrict__ list,
    int* __restrict__ zeroBase /* = (int*)ws */) {
  if (blockIdx.x >= ROWBLKS) {
    const int c = blockIdx.x - ROWBLKS;
    __shared__ int cnt;
    if (threadIdx.x == 0) cnt = 0;
    __syncthreads();
    for (int i = threadIdx.x; i < N; i += 256) {
      if (y[i] == c) {
        const int pos = atomicAdd(&cnt, 1);   // LDS atomic — block-local
        if (pos < CAP) list[c * CAP + pos] = i;
      }
    }
    __syncthreads();
    if (threadIdx.x == 0) counts[c] = (cnt > CAP) ? CAP : cnt;
    return;
  }

  if (blockIdx.x == 0) {
    // zero bytes [400, 2560): done, Bsum, pad, Tsum — 540 ints
    for (int i = threadIdx.x; i < 540; i += 256) zeroBase[100 + i] = 0;
  }

  const int gid  = blockIdx.x * 256 + threadIdx.x;
  const int row  = gid >> 6;
  const int lane = threadIdx.x & 63;

  const float4* ep = reinterpret_cast<const float4*>(e + (size_t)row * D);
  const float4 a = ep[lane];
  const float4 b = ep[lane + 64];
  float ss = a.x * a.x + a.y * a.y + a.z * a.z + a.w * a.w
           + b.x * b.x + b.y * b.y + b.z * b.z + b.w * b.w;
  #pragma unroll
  for (int off = 32; off > 0; off >>= 1) ss += __shfl_xor(ss, off);

  if (lane == 0) invn[row] = 1.0f / sqrtf(ss);
}

// K2 (400 blocks x 512 threads): block (c,s) computes the COMPLETE 128-dim
// slice of S_c (4 row-quarters combined in LDS), then:
//   - atomicAdd slice into Tsum (memory-side, relaxed)
//   - block-local B contribution ||S_c slice||^2 -> atomicAdd(Bsum)
//   - release = per-wave s_waitcnt vmcnt(0) + __syncthreads (NO __threadfence:
//     producers have no dirty L2 lines — only memory-side atomics — so no L2
//     writeback is needed; round 5 showed per-block threadfence costs ~100us)
//   - last block (done-counter) reads Tsum/Bsum with agent-scope loads
//     (613 words, ~3us) and writes the scalar.
__global__ __launch_bounds__(512) void gather_final_kernel(
    const float* __restrict__ e,
    const float* __restrict__ invn,
    const int* __restrict__ counts,
    const int* __restrict__ list,
    float* __restrict__ Tsum,
    float* __restrict__ Bsum,
    int* __restrict__ done,
    float* __restrict__ out) {
  const int c   = blockIdx.x / SLICES;
  const int s   = blockIdx.x % SLICES;
  const int tid = threadIdx.x;   // 0..511
  const int d   = tid & 127;     // dim within slice
  const int q   = tid >> 7;      // row-quarter 0..3

  const int n = counts[c];       // already clamped to CAP by K1

  __shared__ int   ls[CAP];
  __shared__ float li[CAP];
  for (int k = tid; k < n; k += 512) {
    const int r = list[c * CAP + k];
    ls[k] = r;
    li[k] = invn[r];
  }
  __syncthreads();

  const int per = (n + 3) >> 2;
  const int k0  = q * per;
  int k1 = k0 + per;
  if (k1 > n) k1 = n;

  float acc = 0.0f;
  const float* base = e + s * SLICE_D + d;
  #pragma unroll 4
  for (int k = k0; k < k1; ++k) {
    acc += base[(size_t)ls[k] * D] * li[k];
  }

  __shared__ float sh[4][SLICE_D];   // 2 KB
  sh[q][d] = acc;
  __syncthreads();

  if (q == 0) {  // waves 0 and 1 exactly (tid 0..127)
    const float S = sh[0][d] + sh[1][d] + sh[2][d] + sh[3][d];
    atomicAdd(Tsum + s * SLICE_D + d, S);
    float Bp = S * S;
    #pragma unroll
    for (int off = 32; off > 0; off >>= 1) Bp += __shfl_xor(Bp, off);
    if ((tid & 63) == 0) atomicAdd(Bsum, Bp);
  }

  // release: each wave drains its own outstanding (memory-side) atomics,
  // then the block barrier orders all waves before thread 0's done++.
  asm volatile("s_waitcnt vmcnt(0)" ::: "memory");
  __syncthreads();
  __shared__ int lastFlag;
  if (tid == 0) lastFlag = (atomicAdd(done, 1) == GBLOCKS - 1) ? 1 : 0;
  __syncthreads();
  if (!lastFlag) return;

  // ---- finisher: all 400 blocks' atomics are memory-side-complete ----
  const float t = __hip_atomic_load(Tsum + tid, __ATOMIC_RELAXED,
                                    __HIP_MEMORY_SCOPE_AGENT);
  float a2 = t * t;
  #pragma unroll
  for (int off = 32; off > 0; off >>= 1) a2 += __shfl_xor(a2, off);
  int qq = 0;
  if (tid < C) {
    const int nn = counts[tid];  // written by K1: kernel-boundary visible
    qq = nn * nn;
  }
  #pragma unroll
  for (int off = 32; off > 0; off >>= 1) qq += __shfl_xor(qq, off);

  __shared__ float redA[8];
  __shared__ int   redQ[8];
  if ((tid & 63) == 0) {
    redA[tid >> 6] = a2;
    redQ[tid >> 6] = qq;
  }
  __syncthreads();
  if (tid == 0) {
    double A = 0.0, sq = 0.0;
    #pragma unroll
    for (int w = 0; w < 8; ++w) { A += (double)redA[w]; sq += (double)redQ[w]; }
    const double B = (double)__hip_atomic_load(Bsum, __ATOMIC_RELAXED,
                                               __HIP_MEMORY_SCOPE_AGENT);
    out[0] = (float)((A - B) / ((double)N * (double)N - sq));
  }
}

extern "C" void kernel_launch(void* const* d_in, const int* in_sizes, int n_in,
                              void* d_out, int out_size, void* d_ws, size_t ws_size,
                              hipStream_t stream) {
  const float* e = (const float*)d_in[0];
  const int*   y = (const int*)d_in[1];
  float* out = (float*)d_out;

  char* ws = (char*)d_ws;
  int*   counts = (int*)ws;
  int*   done   = (int*)(ws + OFF_DONE);
  float* Bsum   = (float*)(ws + OFF_BSUM);
  float* Tsum   = (float*)(ws + OFF_TSUM);
  float* invn   = (float*)(ws + OFF_INVN);
  int*   list   = (int*)(ws + OFF_LIST);

  norm_list_kernel<<<ROWBLKS + SCANBLKS, 256, 0, stream>>>(e, y, invn, counts,
                                                           list, (int*)ws);
  gather_final_kernel<<<GBLOCKS, 512, 0, stream>>>(e, invn, counts, list,
                                                   Tsum, Bsum, done, out);
}

// Round 10
// 85.325 us; speedup vs baseline: 1.0763x; 1.0763x over previous
//
#include <hip/hip_runtime.h>
#include <hip/hip_bf16.h>

// Problem constants (match setup_inputs): N=8192 rows, D=512 dims, C=100 classes.
constexpr int N = 8192;
constexpr int D = 512;
constexpr int C = 100;
constexpr int CAP = 256;             // per-class list capacity (mean 82, ~19 sigma)
constexpr int SLICES = 4;            // dim slices (128 dims each)
constexpr int SLICE_D = D / SLICES;  // 128
constexpr int CHUNKS = 8;            // row chunks per (class, slice)
constexpr int ROWBLKS = N / 4;       // 2048 blocks of 4 waves, one wave per row
constexpr int SCANBLKS = C;          // 100 list-builder blocks (one per class)

// Workspace layout (bytes) — NOTHING needs pre-zeroing (no memset node):
//   [0, 400)            counts[C]       (int)    — plain-stored by K1 scan blocks
//   [512, 205312)       classSum[C][D]  (float)  — zeroed by K1 row blocks
//   [205312, 238080)    invn[N]         (float)
//   [238080, 340480)    list[C][CAP]    (int)
constexpr size_t OFF_CLASSSUM = 512;
constexpr size_t OFF_INVN     = OFF_CLASSSUM + (size_t)C * D * 4;   // 205312
constexpr size_t OFF_LIST     = OFF_INVN + (size_t)N * 4;           // 238080

// K1 (fused, 2148 blocks):
//  - blocks [0, ROWBLKS): one 64-lane wave per row computes inv norm;
//    first 200 blocks also zero classSum (consumed by K2 across the
//    kernel boundary).
//  - blocks [ROWBLKS, ROWBLKS+C): block per class c scans all labels and
//    builds list[c] + counts[c] using only an LDS-local counter — no
//    global atomics, hence no global zero-init required.
__global__ __launch_bounds__(256) void norm_list_kernel(
    const float* __restrict__ e,
    const int* __restrict__ y,
    float* __restrict__ invn,
    int* __restrict__ counts,
    int* __restrict__ list,
    float* __restrict__ classSum) {
  if (blockIdx.x >= ROWBLKS) {
    // ---- list-builder block for class c ----
    const int c = blockIdx.x - ROWBLKS;
    __shared__ int cnt;
    if (threadIdx.x == 0) cnt = 0;
    __syncthreads();
    for (int i = threadIdx.x; i < N; i += 256) {
      if (y[i] == c) {
        const int pos = atomicAdd(&cnt, 1);   // LDS atomic — cheap, block-local
        if (pos < CAP) list[c * CAP + pos] = i;
      }
    }
    __syncthreads();
    if (threadIdx.x == 0) counts[c] = (cnt > CAP) ? CAP : cnt;
    return;
  }

  // ---- row-norm block ----
  const int gid = blockIdx.x * 256 + threadIdx.x;
  if (gid < C * D) classSum[gid] = 0.0f;  // 51200 elems, first 200 blocks

  const int row  = gid >> 6;
  const int lane = threadIdx.x & 63;

  const float4* ep = reinterpret_cast<const float4*>(e + (size_t)row * D);
  const float4 a = ep[lane];
  const float4 b = ep[lane + 64];
  float ss = a.x * a.x + a.y * a.y + a.z * a.z + a.w * a.w
           + b.x * b.x + b.y * b.y + b.z * b.z + b.w * b.w;
  #pragma unroll
  for (int off = 32; off > 0; off >>= 1) ss += __shfl_xor(ss, off);

  if (lane == 0) invn[row] = 1.0f / sqrtf(ss);
}

// K2: one block per (class c, dim-slice s, row-chunk h). Gathers its ~n/8
// rows, accumulates the partial S_c slice in registers, then ONE atomicAdd
// per element into the zeroed classSum (8-way contention max).
// NO device-scope fences, NO done-counter fusion — rounds 5 and 9 both
// measured intra-kernel global sync losing to the kernel-boundary path.
__global__ __launch_bounds__(128) void gather_kernel(
    const float* __restrict__ e,
    const float* __restrict__ invn,
    const int* __restrict__ counts,
    const int* __restrict__ list,
    float* __restrict__ classSum) {
  const int c   = blockIdx.x / (SLICES * CHUNKS);
  const int rem = blockIdx.x % (SLICES * CHUNKS);
  const int s   = rem / CHUNKS;
  const int h   = rem % CHUNKS;
  const int tid = threadIdx.x;  // 0..127, owns dim s*128 + tid

  const int n = counts[c];                     // already clamped to CAP
  const int per = (n + CHUNKS - 1) / CHUNKS;   // <= 32
  const int k0  = h * per;
  int k1 = k0 + per;
  if (k1 > n) k1 = n;
  const int m = k1 - k0;                       // rows this block handles
  if (m <= 0) return;

  __shared__ int   ls[CAP / CHUNKS];           // 32
  __shared__ float li[CAP / CHUNKS];
  if (tid < m) {
    const int r = list[c * CAP + k0 + tid];
    ls[tid] = r;
    li[tid] = invn[r];
  }
  __syncthreads();

  float acc = 0.0f;
  const float* base = e + s * SLICE_D + tid;
  #pragma unroll 4
  for (int k = 0; k < m; ++k) {
    acc += base[(size_t)ls[k] * D] * li[k];
  }

  atomicAdd(classSum + c * D + s * SLICE_D + tid, acc);
}

// K3: A = ||sum_c S_c||^2, B = sum_c ||S_c||^2, sq = sum_c n_c^2 — all
// parallel LDS-tree reductions.  loss = (A - B) / (N^2 - sq).
__global__ __launch_bounds__(512) void final_kernel(
    const float* __restrict__ classSum,
    const int* __restrict__ counts,
    float* __restrict__ out) {
  const int d = threadIdx.x;  // 0..511, one dim each
  float t = 0.0f, b = 0.0f;
  #pragma unroll 10
  for (int c = 0; c < C; ++c) {
    const float v = classSum[c * D + d];
    t += v;
    b += v * v;
  }
  __shared__ float shA[512];
  __shared__ float shB[512];
  __shared__ float shQ[512];
  shA[d] = t * t;
  shB[d] = b;
  if (d < C) {
    const float n = (float)counts[d];
    shQ[d] = n * n;
  } else {
    shQ[d] = 0.0f;
  }
  __syncthreads();
  for (int off = 256; off > 0; off >>= 1) {
    if (d < off) {
      shA[d] += shA[d + off];
      shB[d] += shB[d + off];
      shQ[d] += shQ[d + off];
    }
    __syncthreads();
  }
  if (d == 0) {
    const double A  = (double)shA[0];
    const double B  = (double)shB[0];
    const double sq = (double)shQ[0];
    out[0] = (float)((A - B) / ((double)N * (double)N - sq));
  }
}

extern "C" void kernel_launch(void* const* d_in, const int* in_sizes, int n_in,
                              void* d_out, int out_size, void* d_ws, size_t ws_size,
                              hipStream_t stream) {
  const float* e = (const float*)d_in[0];
  const int*   y = (const int*)d_in[1];
  float* out = (float*)d_out;

  char* ws = (char*)d_ws;
  int*   counts   = (int*)ws;
  float* classSum = (float*)(ws + OFF_CLASSSUM);
  float* invn     = (float*)(ws + OFF_INVN);
  int*   list     = (int*)(ws + OFF_LIST);

  // No memset node: counts is plain-stored by K1's scan blocks, classSum is
  // zeroed by K1's row blocks. Nothing reads stale/poisoned ws bytes.
  norm_list_kernel<<<ROWBLKS + SCANBLKS, 256, 0, stream>>>(e, y, invn, counts,
                                                           list, classSum);
  gather_kernel<<<C * SLICES * CHUNKS, 128, 0, stream>>>(e, invn, counts, list,
                                                         classSum);
  final_kernel<<<1, 512, 0, stream>>>(classSum, counts, out);
}